// Round 1
// baseline (253.221 us; speedup 1.0000x reference)
//
#include <hip/hip_runtime.h>

// 3D window attention (Swin-style), fully fused per 4x4x4 window.
// x:(2,64,64,64,96) f32, w_qkv:(96,288), pos:(7,7,7), w_out:(96,96), b_out:(96)
// heads=3, head_dim=32, T=64 tokens/window, 8192 windows total.

typedef __attribute__((ext_vector_type(8))) short bv8;   // 8 bf16 (4 VGPRs) MFMA frag
typedef __attribute__((ext_vector_type(4))) float fv4;   // MFMA accumulator

__device__ inline unsigned short f2bf(float f) {
    union { float f; unsigned u; } v; v.f = f;
    unsigned r = v.u + 0x7fffu + ((v.u >> 16) & 1u);   // RNE
    return (unsigned short)(r >> 16);
}

// ---- prep: transpose weights to (N,K) bf16, build 64x64 bias table ----
// work items: 27648 (wqT) + 9216 (woT) + 4096 (bias) = 40960 -> 160 blocks
__global__ void prep_kernel(const float* __restrict__ wqkv,
                            const float* __restrict__ wout,
                            const float* __restrict__ pos,
                            float* __restrict__ bias,
                            unsigned short* __restrict__ wqT,
                            unsigned short* __restrict__ woT)
{
    int id = blockIdx.x * 256 + threadIdx.x;
    if (id < 27648) {                       // wqT[n][k] = w_qkv[k][n], n<288 k<96
        int n = id / 96, k = id % 96;
        wqT[id] = f2bf(wqkv[k * 288 + n]);
    } else if (id < 36864) {                // woT[n][k] = w_out[k][n], n<96 k<96
        int j = id - 27648;
        int n = j / 96, k = j % 96;
        woT[j] = f2bf(wout[k * 96 + n]);
    } else {                                // bias[i][j] = pos[dj-di+3 ...]
        int i = id - 36864;
        int qi = i >> 6, kj = i & 63;
        int dh = ((kj >> 4) & 3) - ((qi >> 4) & 3) + 3;
        int dw = ((kj >> 2) & 3) - ((qi >> 2) & 3) + 3;
        int dd = (kj & 3) - (qi & 3) + 3;
        bias[i] = pos[(dh * 7 + dw) * 7 + dd];
    }
}

// ---- fused window attention: 1 block = 1 window (64 tokens), 4 waves ----
__global__ void __launch_bounds__(256, 2) winattn_kernel(
    const float* __restrict__ x,
    const float* __restrict__ b_out,
    const float* __restrict__ bias,
    const unsigned short* __restrict__ wqT,
    const unsigned short* __restrict__ woT,
    float* __restrict__ out)
{
    // LDS: 12288 + 13312 + 12288 + 13824 + 13312 + 256 = 65280 B (<= 64 KiB)
    __shared__ __align__(16) unsigned short xs[64 * 96];    // x tile; reused as ps[64*72]
    __shared__ __align__(16) unsigned short qs[64 * 104];   // Q row-major, padded stride
    __shared__ __align__(16) unsigned short ks[64 * 96];    // K row-major
    __shared__ __align__(16) unsigned short vts[96 * 72];   // V transposed [d][j]
    __shared__ __align__(16) unsigned short aout[64 * 104]; // attention out, token-major
    __shared__ int toff[64];                                // token -> global f32 offset

    const int tid = threadIdx.x;
    const int w = tid >> 6;            // wave 0..3
    const int lane = tid & 63;
    const int c = lane & 15;           // MFMA row/col index
    const int g = lane >> 4;           // MFMA k-group / row-group
    const int widx = blockIdx.x;       // window index (16x16x16)
    const int bb = blockIdx.y;         // batch
    const int bh = (widx >> 8) & 15, bw2 = (widx >> 4) & 15, bd = widx & 15;

    if (tid < 64) {
        int t = tid;
        int gh = bh * 4 + (t >> 4), gw = bw2 * 4 + ((t >> 2) & 3), gd = bd * 4 + (t & 3);
        toff[t] = (((bb * 64 + gh) * 64 + gw) * 64 + gd) * 96;
    }

    // ---------- phase 1: load x window -> bf16 LDS ----------
    for (int idx = tid; idx < 64 * 24; idx += 256) {
        int t = idx / 24, c4 = idx % 24;
        int gh = bh * 4 + (t >> 4), gw = bw2 * 4 + ((t >> 2) & 3), gd = bd * 4 + (t & 3);
        int off = (((bb * 64 + gh) * 64 + gw) * 64 + gd) * 96 + c4 * 4;
        float4 xv = *(const float4*)(x + off);
        unsigned p0 = (unsigned)f2bf(xv.x) | ((unsigned)f2bf(xv.y) << 16);
        unsigned p1 = (unsigned)f2bf(xv.z) | ((unsigned)f2bf(xv.w) << 16);
        *(unsigned*)&xs[t * 96 + c4 * 4]     = p0;
        *(unsigned*)&xs[t * 96 + c4 * 4 + 2] = p1;
    }
    __syncthreads();

    // ---------- phase 2: QKV = X @ Wqkv (M=64,N=288,K=96) ----------
    // A-fragments (all 64 rows x 96 k) preloaded to registers: 12 frags/wave
    bv8 af[4][3];
#pragma unroll
    for (int mt = 0; mt < 4; ++mt)
#pragma unroll
        for (int k = 0; k < 3; ++k)
            af[mt][k] = *(const bv8*)&xs[(mt * 16 + c) * 96 + k * 32 + g * 8];

    for (int nt = w; nt < 18; nt += 4) {     // N-tiles round-robin over waves
        bv8 bf[3];
#pragma unroll
        for (int k = 0; k < 3; ++k)
            bf[k] = *(const bv8*)(wqT + (nt * 16 + c) * 96 + k * 32 + g * 8);
#pragma unroll
        for (int mt = 0; mt < 4; ++mt) {
            fv4 acc = {0.f, 0.f, 0.f, 0.f};
#pragma unroll
            for (int k = 0; k < 3; ++k)
                acc = __builtin_amdgcn_mfma_f32_16x16x32_bf16(af[mt][k], bf[k], acc, 0, 0, 0);
            int row = mt * 16 + 4 * g;       // + r -> D row; col = nt*16 + c
            if (nt < 6) {
#pragma unroll
                for (int r = 0; r < 4; ++r)
                    qs[(row + r) * 104 + nt * 16 + c] = f2bf(acc[r]);
            } else if (nt < 12) {
#pragma unroll
                for (int r = 0; r < 4; ++r)
                    ks[(row + r) * 96 + (nt - 6) * 16 + c] = f2bf(acc[r]);
            } else {                         // V: store transposed [d][token]
                int d = (nt - 12) * 16 + c;
                unsigned q0 = (unsigned)f2bf(acc[0]) | ((unsigned)f2bf(acc[1]) << 16);
                unsigned q1 = (unsigned)f2bf(acc[2]) | ((unsigned)f2bf(acc[3]) << 16);
                *(unsigned*)&vts[d * 72 + row]     = q0;
                *(unsigned*)&vts[d * 72 + row + 2] = q1;
            }
        }
    }
    __syncthreads();

    // ---------- phase 3: attention, wave w owns rows [16w,16w+16) ----------
    const float scale = 0.17677669529663687f;   // 32^-0.5
    unsigned short* ps = xs;                    // P tile (bf16), stride 72, per-wave rows
    const int i0 = w * 16;

    float brow[4][4];                           // bias, reused across heads
#pragma unroll
    for (int nt = 0; nt < 4; ++nt)
#pragma unroll
        for (int r = 0; r < 4; ++r)
            brow[nt][r] = bias[(i0 + 4 * g + r) * 64 + nt * 16 + c];

    for (int h = 0; h < 3; ++h) {
        bv8 qf = *(const bv8*)&qs[(i0 + c) * 104 + h * 32 + g * 8];
        float sv[4][4];
#pragma unroll
        for (int nt = 0; nt < 4; ++nt) {
            bv8 kf = *(const bv8*)&ks[(nt * 16 + c) * 96 + h * 32 + g * 8];
            fv4 z = {0.f, 0.f, 0.f, 0.f};
            fv4 s = __builtin_amdgcn_mfma_f32_16x16x32_bf16(qf, kf, z, 0, 0, 0);
#pragma unroll
            for (int r = 0; r < 4; ++r)
                sv[nt][r] = s[r] * scale + brow[nt][r];
        }
        // softmax over 64 cols of each of this lane-group's 4 rows
        float mx[4], sm[4];
#pragma unroll
        for (int r = 0; r < 4; ++r)
            mx[r] = fmaxf(fmaxf(sv[0][r], sv[1][r]), fmaxf(sv[2][r], sv[3][r]));
#pragma unroll
        for (int m = 1; m <= 8; m <<= 1)
#pragma unroll
            for (int r = 0; r < 4; ++r)
                mx[r] = fmaxf(mx[r], __shfl_xor(mx[r], m, 64));
#pragma unroll
        for (int r = 0; r < 4; ++r) sm[r] = 0.f;
#pragma unroll
        for (int nt = 0; nt < 4; ++nt)
#pragma unroll
            for (int r = 0; r < 4; ++r) {
                float e = __expf(sv[nt][r] - mx[r]);
                sv[nt][r] = e;
                sm[r] += e;
            }
#pragma unroll
        for (int m = 1; m <= 8; m <<= 1)
#pragma unroll
            for (int r = 0; r < 4; ++r)
                sm[r] += __shfl_xor(sm[r], m, 64);
        float inv[4];
#pragma unroll
        for (int r = 0; r < 4; ++r) inv[r] = 1.0f / sm[r];

        // unnormalized P -> LDS (normalize after PV)
#pragma unroll
        for (int nt = 0; nt < 4; ++nt)
#pragma unroll
            for (int r = 0; r < 4; ++r)
                ps[(i0 + 4 * g + r) * 72 + nt * 16 + c] = f2bf(sv[nt][r]);

        // O = P @ V (M=16 strip, N=32, K=64)
#pragma unroll
        for (int dt = 0; dt < 2; ++dt) {
            fv4 oacc = {0.f, 0.f, 0.f, 0.f};
#pragma unroll
            for (int k2 = 0; k2 < 2; ++k2) {
                bv8 pf = *(const bv8*)&ps[(i0 + c) * 72 + k2 * 32 + g * 8];
                bv8 vf = *(const bv8*)&vts[(h * 32 + dt * 16 + c) * 72 + k2 * 32 + g * 8];
                oacc = __builtin_amdgcn_mfma_f32_16x16x32_bf16(pf, vf, oacc, 0, 0, 0);
            }
#pragma unroll
            for (int r = 0; r < 4; ++r)
                aout[(i0 + 4 * g + r) * 104 + h * 32 + dt * 16 + c] = f2bf(oacc[r] * inv[r]);
        }
    }
    __syncthreads();

    // ---------- phase 4: out = A @ Wout + b (M=64,N=96,K=96) ----------
    bv8 afo[3];
#pragma unroll
    for (int k = 0; k < 3; ++k)
        afo[k] = *(const bv8*)&aout[(i0 + c) * 104 + k * 32 + g * 8];
#pragma unroll
    for (int nt = 0; nt < 6; ++nt) {
        fv4 acc = {0.f, 0.f, 0.f, 0.f};
#pragma unroll
        for (int k = 0; k < 3; ++k) {
            bv8 bf = *(const bv8*)(woT + (nt * 16 + c) * 96 + k * 32 + g * 8);
            acc = __builtin_amdgcn_mfma_f32_16x16x32_bf16(afo[k], bf, acc, 0, 0, 0);
        }
        int cc = nt * 16 + c;
        float bo = b_out[cc];
#pragma unroll
        for (int r = 0; r < 4; ++r) {
            int row = i0 + 4 * g + r;
            out[toff[row] + cc] = acc[r] + bo;
        }
    }
}

extern "C" void kernel_launch(void* const* d_in, const int* in_sizes, int n_in,
                              void* d_out, int out_size, void* d_ws, size_t ws_size,
                              hipStream_t stream)
{
    const float* x    = (const float*)d_in[0];
    const float* wqkv = (const float*)d_in[1];
    const float* pos  = (const float*)d_in[2];
    const float* wout = (const float*)d_in[3];
    const float* bout = (const float*)d_in[4];
    float* out = (float*)d_out;

    // ws layout: bias f32[4096] @0 (16384B) | wqT bf16[288*96] @16384 (55296B)
    //            | woT bf16[96*96] @71680 (18432B)
    float* bias = (float*)d_ws;
    unsigned short* wqT = (unsigned short*)((char*)d_ws + 16384);
    unsigned short* woT = (unsigned short*)((char*)d_ws + 16384 + 55296);

    prep_kernel<<<160, 256, 0, stream>>>(wqkv, wout, pos, bias, wqT, woT);
    winattn_kernel<<<dim3(4096, 2), 256, 0, stream>>>(x, bout, bias, wqT, woT, out);
}

// Round 2
// 205.941 us; speedup vs baseline: 1.2296x; 1.2296x over previous
//
#include <hip/hip_runtime.h>

// 3D window attention (Swin-style), fully fused per 4x4x4 window.
// x:(2,64,64,64,96) f32, w_qkv:(96,288), pos:(7,7,7), w_out:(96,96), b_out:(96)
// heads=3, head_dim=32, T=64 tokens/window, 8192 windows total.

typedef __attribute__((ext_vector_type(8))) short bv8;   // 8 bf16 MFMA frag
typedef __attribute__((ext_vector_type(4))) float fv4;   // MFMA accumulator

__device__ __forceinline__ unsigned short f2bf(float f) {
    union { float f; unsigned u; } v; v.f = f;
    unsigned r = v.u + 0x7fffu + ((v.u >> 16) & 1u);   // RNE
    return (unsigned short)(r >> 16);
}

__device__ __forceinline__ bv8 cvt8(const float* __restrict__ p) {
    float4 a = *(const float4*)p;
    float4 b = *(const float4*)(p + 4);
    bv8 r;
    r[0] = (short)f2bf(a.x); r[1] = (short)f2bf(a.y);
    r[2] = (short)f2bf(a.z); r[3] = (short)f2bf(a.w);
    r[4] = (short)f2bf(b.x); r[5] = (short)f2bf(b.y);
    r[6] = (short)f2bf(b.z); r[7] = (short)f2bf(b.w);
    return r;
}

// ---- prep: transpose weights to (N,K) bf16, build 64x64 bias table ----
__global__ void prep_kernel(const float* __restrict__ wqkv,
                            const float* __restrict__ wout,
                            const float* __restrict__ pos,
                            float* __restrict__ bias,
                            unsigned short* __restrict__ wqT,
                            unsigned short* __restrict__ woT)
{
    int id = blockIdx.x * 256 + threadIdx.x;
    if (id < 27648) {                       // wqT[n][k] = w_qkv[k][n], n<288 k<96
        int n = id / 96, k = id % 96;
        wqT[id] = f2bf(wqkv[k * 288 + n]);
    } else if (id < 36864) {                // woT[n][k] = w_out[k][n], n<96 k<96
        int j = id - 27648;
        int n = j / 96, k = j % 96;
        woT[j] = f2bf(wout[k * 96 + n]);
    } else {                                // bias[i][j] from pos_embedding
        int i = id - 36864;
        int qi = i >> 6, kj = i & 63;
        int dh = ((kj >> 4) & 3) - ((qi >> 4) & 3) + 3;
        int dw = ((kj >> 2) & 3) - ((qi >> 2) & 3) + 3;
        int dd = (kj & 3) - (qi & 3) + 3;
        bias[i] = pos[(dh * 7 + dw) * 7 + dd];
    }
}

// ---- fused window attention: 1 block = 1 window (64 tokens), 4 waves ----
// LDS 49664 B -> 3 blocks/CU. One barrier total (after QKV projection).
__global__ void __launch_bounds__(256, 3) winattn_kernel(
    const float* __restrict__ x,
    const float* __restrict__ b_out,
    const float* __restrict__ bias,
    const unsigned short* __restrict__ wqT,
    const unsigned short* __restrict__ woT,
    float* __restrict__ out)
{
    __shared__ __align__(16) unsigned short qs[64 * 104];  // Q; aout overlay in ph3/4
    __shared__ __align__(16) unsigned short ks[64 * 104];  // K row-major, stride 104
    __shared__ __align__(16) unsigned short vts[96 * 72];  // V transposed [d][tok]
    __shared__ __align__(16) unsigned short ps[4 * 16 * 72]; // per-wave P strip

    const int tid = threadIdx.x;
    const int w = tid >> 6, lane = tid & 63;
    const int c = lane & 15, g = lane >> 4;
    const int widx = blockIdx.x, bb = blockIdx.y;
    const int bh = (widx >> 8) & 15, bw2 = (widx >> 4) & 15, bd = widx & 15;

    const int ST_W = 64 * 96, ST_H = 64 * 64 * 96;
    const int xbase = ((bb * 64 + bh * 4) * 64 + bw2 * 4) * 64 * 96 + bd * 4 * 96;
    const int i0 = w * 16;

    // ---------- A-fragments: direct global -> bf16 regs (own 2 strips) ----------
    const int mt0 = (w & 1) * 2;          // strips {mt0, mt0+1}
    const int ntbase = (w >> 1) * 9;      // nt range [ntbase, ntbase+9)
    bv8 af[2][3];
#pragma unroll
    for (int m2 = 0; m2 < 2; ++m2) {
        int t = (mt0 + m2) * 16 + c;
        const float* tp = x + xbase + (t >> 4) * ST_H + ((t >> 2) & 3) * ST_W + (t & 3) * 96;
#pragma unroll
        for (int k = 0; k < 3; ++k)
            af[m2][k] = cvt8(tp + k * 32 + g * 8);
    }

    // bias rows for this lane (used in phase 3) — issue loads early
    float brow[4][4];
#pragma unroll
    for (int nt = 0; nt < 4; ++nt)
#pragma unroll
        for (int r = 0; r < 4; ++r)
            brow[nt][r] = bias[(i0 + 4 * g + r) * 64 + nt * 16 + c];

    // ---------- phase 2: QKV = X @ Wqkv, 18 tiles/wave, B-prefetch ----------
    const unsigned short* bsrc = wqT + c * 96 + g * 8;   // + nt*1536 + k*32
    bv8 b0[3], bn[3];
#pragma unroll
    for (int k = 0; k < 3; ++k) b0[k] = *(const bv8*)(bsrc + ntbase * 1536 + k * 32);

#pragma unroll
    for (int i = 0; i < 9; ++i) {
        const int nt = ntbase + i;
        if (i < 8) {
#pragma unroll
            for (int k = 0; k < 3; ++k) bn[k] = *(const bv8*)(bsrc + (nt + 1) * 1536 + k * 32);
        }
        fv4 acc0 = {0.f, 0.f, 0.f, 0.f}, acc1 = {0.f, 0.f, 0.f, 0.f};
#pragma unroll
        for (int k = 0; k < 3; ++k) {
            acc0 = __builtin_amdgcn_mfma_f32_16x16x32_bf16(af[0][k], b0[k], acc0, 0, 0, 0);
            acc1 = __builtin_amdgcn_mfma_f32_16x16x32_bf16(af[1][k], b0[k], acc1, 0, 0, 0);
        }
#pragma unroll
        for (int m2 = 0; m2 < 2; ++m2) {
            const fv4& acc = m2 ? acc1 : acc0;
            int row = (mt0 + m2) * 16 + 4 * g;
            if (nt < 6) {
                int col = nt * 16 + c;
#pragma unroll
                for (int r = 0; r < 4; ++r) qs[(row + r) * 104 + col] = f2bf(acc[r]);
            } else if (nt < 12) {
                int col = (nt - 6) * 16 + c;
#pragma unroll
                for (int r = 0; r < 4; ++r) ks[(row + r) * 104 + col] = f2bf(acc[r]);
            } else {
                int d = (nt - 12) * 16 + c;
                unsigned q0 = (unsigned)f2bf(acc[0]) | ((unsigned)f2bf(acc[1]) << 16);
                unsigned q1 = (unsigned)f2bf(acc[2]) | ((unsigned)f2bf(acc[3]) << 16);
                *(unsigned*)&vts[d * 72 + row]     = q0;
                *(unsigned*)&vts[d * 72 + row + 2] = q1;
            }
        }
        if (i < 8) {
#pragma unroll
            for (int k = 0; k < 3; ++k) b0[k] = bn[k];
        }
    }
    __syncthreads();   // the only barrier

    // ---------- phase 3: attention on own 16-row strip (wave-independent) ----------
    const float scale = 0.17677669529663687f;   // 32^-0.5
    unsigned short* pw = ps + w * (16 * 72);

    bv8 qf[3];
#pragma unroll
    for (int h = 0; h < 3; ++h)
        qf[h] = *(const bv8*)&qs[(i0 + c) * 104 + h * 32 + g * 8];

#pragma unroll
    for (int h = 0; h < 3; ++h) {
        bv8 kf[4];
#pragma unroll
        for (int nt = 0; nt < 4; ++nt)
            kf[nt] = *(const bv8*)&ks[(nt * 16 + c) * 104 + h * 32 + g * 8];
        float sv[4][4];
#pragma unroll
        for (int nt = 0; nt < 4; ++nt) {
            fv4 z = {0.f, 0.f, 0.f, 0.f};
            fv4 s = __builtin_amdgcn_mfma_f32_16x16x32_bf16(qf[h], kf[nt], z, 0, 0, 0);
#pragma unroll
            for (int r = 0; r < 4; ++r)
                sv[nt][r] = s[r] * scale + brow[nt][r];
        }
        // softmax across 64 cols (cols live on the 16 lanes of this g-group)
        float mx[4], sm[4];
#pragma unroll
        for (int r = 0; r < 4; ++r)
            mx[r] = fmaxf(fmaxf(sv[0][r], sv[1][r]), fmaxf(sv[2][r], sv[3][r]));
#pragma unroll
        for (int m = 1; m <= 8; m <<= 1)
#pragma unroll
            for (int r = 0; r < 4; ++r)
                mx[r] = fmaxf(mx[r], __shfl_xor(mx[r], m, 64));
#pragma unroll
        for (int r = 0; r < 4; ++r) sm[r] = 0.f;
#pragma unroll
        for (int nt = 0; nt < 4; ++nt)
#pragma unroll
            for (int r = 0; r < 4; ++r) {
                float e = __expf(sv[nt][r] - mx[r]);
                sv[nt][r] = e;
                sm[r] += e;
            }
#pragma unroll
        for (int m = 1; m <= 8; m <<= 1)
#pragma unroll
            for (int r = 0; r < 4; ++r)
                sm[r] += __shfl_xor(sm[r], m, 64);
        float inv[4];
#pragma unroll
        for (int r = 0; r < 4; ++r) inv[r] = __builtin_amdgcn_rcpf(sm[r]);

        // unnormalized P -> private LDS strip, then PV
#pragma unroll
        for (int nt = 0; nt < 4; ++nt)
#pragma unroll
            for (int r = 0; r < 4; ++r)
                pw[(4 * g + r) * 72 + nt * 16 + c] = f2bf(sv[nt][r]);

        bv8 pf[2];
#pragma unroll
        for (int k2 = 0; k2 < 2; ++k2)
            pf[k2] = *(const bv8*)&pw[c * 72 + k2 * 32 + g * 8];

#pragma unroll
        for (int dt = 0; dt < 2; ++dt) {
            fv4 oacc = {0.f, 0.f, 0.f, 0.f};
#pragma unroll
            for (int k2 = 0; k2 < 2; ++k2) {
                bv8 vf = *(const bv8*)&vts[(h * 32 + dt * 16 + c) * 72 + k2 * 32 + g * 8];
                oacc = __builtin_amdgcn_mfma_f32_16x16x32_bf16(pf[k2], vf, oacc, 0, 0, 0);
            }
            // attention out -> qs overlay (own strip only; qf already in regs)
#pragma unroll
            for (int r = 0; r < 4; ++r)
                qs[(i0 + 4 * g + r) * 104 + h * 32 + dt * 16 + c] = f2bf(oacc[r] * inv[r]);
        }
    }

    // ---------- phase 4: out = A @ Wout + b (no barrier: own strip only) ----------
    bv8 afo[3];
#pragma unroll
    for (int k = 0; k < 3; ++k)
        afo[k] = *(const bv8*)&qs[(i0 + c) * 104 + k * 32 + g * 8];

    const unsigned short* osrc = woT + c * 96 + g * 8;
    bv8 ob0[3], obn[3];
#pragma unroll
    for (int k = 0; k < 3; ++k) ob0[k] = *(const bv8*)(osrc + k * 32);

#pragma unroll
    for (int nt = 0; nt < 6; ++nt) {
        if (nt < 5) {
#pragma unroll
            for (int k = 0; k < 3; ++k) obn[k] = *(const bv8*)(osrc + (nt + 1) * 1536 + k * 32);
        }
        fv4 acc = {0.f, 0.f, 0.f, 0.f};
#pragma unroll
        for (int k = 0; k < 3; ++k)
            acc = __builtin_amdgcn_mfma_f32_16x16x32_bf16(afo[k], ob0[k], acc, 0, 0, 0);
        int cc = nt * 16 + c;
        float bo = b_out[cc];
#pragma unroll
        for (int r = 0; r < 4; ++r) {
            int t = i0 + 4 * g + r;
            out[xbase + (t >> 4) * ST_H + ((t >> 2) & 3) * ST_W + (t & 3) * 96 + cc] = acc[r] + bo;
        }
        if (nt < 5) {
#pragma unroll
            for (int k = 0; k < 3; ++k) ob0[k] = obn[k];
        }
    }
}

extern "C" void kernel_launch(void* const* d_in, const int* in_sizes, int n_in,
                              void* d_out, int out_size, void* d_ws, size_t ws_size,
                              hipStream_t stream)
{
    const float* x    = (const float*)d_in[0];
    const float* wqkv = (const float*)d_in[1];
    const float* pos  = (const float*)d_in[2];
    const float* wout = (const float*)d_in[3];
    const float* bout = (const float*)d_in[4];
    float* out = (float*)d_out;

    float* bias = (float*)d_ws;
    unsigned short* wqT = (unsigned short*)((char*)d_ws + 16384);
    unsigned short* woT = (unsigned short*)((char*)d_ws + 16384 + 55296);

    prep_kernel<<<160, 256, 0, stream>>>(wqkv, wout, pos, bias, wqT, woT);
    winattn_kernel<<<dim3(4096, 2), 256, 0, stream>>>(x, bout, bias, wqT, woT, out);
}

// Round 4
// 205.187 us; speedup vs baseline: 1.2341x; 1.0037x over previous
//
#include <hip/hip_runtime.h>

// 3D window attention (Swin-style), fully fused per 4x4x4 window.
// x:(2,64,64,64,96) f32, w_qkv:(96,288), pos:(7,7,7), w_out:(96,96), b_out:(96)
// heads=3, head_dim=32, T=64 tokens/window, 8192 windows.

typedef __attribute__((ext_vector_type(8))) short bv8;   // 8 bf16 MFMA frag
typedef __attribute__((ext_vector_type(4))) float fv4;   // MFMA accumulator

__device__ __forceinline__ unsigned short f2bf(float f) {
    union { float f; unsigned u; } v; v.f = f;
    unsigned r = v.u + 0x7fffu + ((v.u >> 16) & 1u);   // RNE
    return (unsigned short)(r >> 16);
}

__device__ __forceinline__ unsigned pack2(float lo, float hi) {   // 2 f32 -> bf16x2
    return (unsigned)f2bf(lo) | ((unsigned)f2bf(hi) << 16);
}

__device__ __forceinline__ bv8 cvt8(const float* __restrict__ p) {
    float4 a = *(const float4*)p;
    float4 b = *(const float4*)(p + 4);
    bv8 r;
    r[0] = (short)f2bf(a.x); r[1] = (short)f2bf(a.y);
    r[2] = (short)f2bf(a.z); r[3] = (short)f2bf(a.w);
    r[4] = (short)f2bf(b.x); r[5] = (short)f2bf(b.y);
    r[6] = (short)f2bf(b.z); r[7] = (short)f2bf(b.w);
    return r;
}

// ---- prep: transpose weights to (N,K) bf16, transposed+log2e-scaled bias ----
__global__ void prep_kernel(const float* __restrict__ wqkv,
                            const float* __restrict__ wout,
                            const float* __restrict__ pos,
                            float* __restrict__ biasT,
                            unsigned short* __restrict__ wqT,
                            unsigned short* __restrict__ woT)
{
    int id = blockIdx.x * 256 + threadIdx.x;
    if (id < 27648) {                       // wqT[n][k] = w_qkv[k][n]
        int n = id / 96, k = id % 96;
        wqT[id] = f2bf(wqkv[k * 288 + n]);
    } else if (id < 36864) {                // woT[n][k] = w_out[k][n]
        int j = id - 27648;
        int n = j / 96, k = j % 96;
        woT[j] = f2bf(wout[k * 96 + n]);
    } else {                                // biasT[kj][qi] = pos[rel] * log2(e)
        int i = id - 36864;
        int kj = i >> 6, qi = i & 63;
        int dh = ((kj >> 4) & 3) - ((qi >> 4) & 3) + 3;
        int dw = ((kj >> 2) & 3) - ((qi >> 2) & 3) + 3;
        int dd = (kj & 3) - (qi & 3) + 3;
        biasT[kj * 64 + qi] = pos[(dh * 7 + dw) * 7 + dd] * 1.4426950408889634f;
    }
}

// ---- fused window attention: 1 block = 1 window, 4 waves, 40448 B LDS ----
__global__ void __launch_bounds__(256, 4) winattn_kernel(
    const float* __restrict__ x,
    const float* __restrict__ b_out,
    const float* __restrict__ biasT,
    const unsigned short* __restrict__ wqT,
    const unsigned short* __restrict__ woT,
    float* __restrict__ out)
{
    __shared__ __align__(16) unsigned short au[4 * 16 * 104]; // per-wave Q -> attn-out
    __shared__ __align__(16) unsigned short ks[64 * 104];     // K row-major
    __shared__ __align__(16) unsigned short vts[96 * 72];     // V^T [d][token]

    const int tid = threadIdx.x;
    const int w = tid >> 6, lane = tid & 63;
    const int c = lane & 15, g = lane >> 4;
    const int widx = blockIdx.x, bb = blockIdx.y;
    const int bh = (widx >> 8) & 15, bw2 = (widx >> 4) & 15, bd = widx & 15;

    const int ST_W = 64 * 96, ST_H = 64 * 64 * 96;
    const int xbase = ((bb * 64 + bh * 4) * 64 + bw2 * 4) * 64 * 96 + bd * 4 * 96;
    const int i0 = w * 16;
    unsigned short* auw = au + w * (16 * 104);

    // ---- A-fragments: own strip (token t = i0 + c), global -> bf16 regs ----
    bv8 af[3];
    {
        int t = i0 + c;
        const float* tp = x + xbase + (t >> 4) * ST_H + ((t >> 2) & 3) * ST_W + (t & 3) * 96;
#pragma unroll
        for (int k = 0; k < 3; ++k)
            af[k] = cvt8(tp + k * 32 + g * 8);
    }

    // bias rows (transposed table, coalesced across c), log2e pre-folded
    float brow[4][4];
#pragma unroll
    for (int nt = 0; nt < 4; ++nt)
#pragma unroll
        for (int r = 0; r < 4; ++r)
            brow[nt][r] = biasT[(nt * 16 + 4 * g + r) * 64 + i0 + c];

    // ---- phase 2: QKV = X @ Wqkv. Each wave: its 16 tokens x all 288 cols ----
    const unsigned short* bsrc = wqT + c * 96 + g * 8;
    bv8 b0[3], bn[3];
#pragma unroll
    for (int k = 0; k < 3; ++k) b0[k] = *(const bv8*)(bsrc + k * 32);

#pragma unroll
    for (int nt = 0; nt < 18; ++nt) {
        if (nt < 17) {
#pragma unroll
            for (int k = 0; k < 3; ++k) bn[k] = *(const bv8*)(bsrc + (nt + 1) * 1536 + k * 32);
        }
        fv4 acc = {0.f, 0.f, 0.f, 0.f};
#pragma unroll
        for (int k = 0; k < 3; ++k)
            acc = __builtin_amdgcn_mfma_f32_16x16x32_bf16(af[k], b0[k], acc, 0, 0, 0);
        if (nt < 6) {            // Q -> own per-wave strip (local rows 4g+r)
#pragma unroll
            for (int r = 0; r < 4; ++r)
                auw[(4 * g + r) * 104 + nt * 16 + c] = f2bf(acc[r]);
        } else if (nt < 12) {    // K -> shared, token rows i0+4g+r
#pragma unroll
            for (int r = 0; r < 4; ++r)
                ks[(i0 + 4 * g + r) * 104 + (nt - 6) * 16 + c] = f2bf(acc[r]);
        } else {                 // V -> transposed [d][token], packed pair writes
            int d = (nt - 12) * 16 + c;
            *(unsigned*)&vts[d * 72 + i0 + 4 * g]     = pack2(acc[0], acc[1]);
            *(unsigned*)&vts[d * 72 + i0 + 4 * g + 2] = pack2(acc[2], acc[3]);
        }
#pragma unroll
        for (int k = 0; k < 3; ++k) b0[k] = bn[k];
    }
    __syncthreads();   // K,V (and own Q) visibility — the only barrier

    // qf: Q fragments for own strip
    bv8 qf[3];
#pragma unroll
    for (int h = 0; h < 3; ++h)
        qf[h] = *(const bv8*)&auw[c * 104 + h * 32 + g * 8];

    // ---- phase 3: swapped QK^T attention; wave owns q-rows i0..i0+15 ----
    const float scale2 = 0.17677669529663687f * 1.4426950408889634f; // scale*log2e
    const int lsrc0 = (((2 * g) & 3) << 4) + c;
    const int lsrc1 = (((2 * g + 1) & 3) << 4) + c;
    const bool selhi = (g & 2) != 0;

#pragma unroll
    for (int h = 0; h < 3; ++h) {
        bv8 kf[4];
#pragma unroll
        for (int nt = 0; nt < 4; ++nt)
            kf[nt] = *(const bv8*)&ks[(nt * 16 + c) * 104 + h * 32 + g * 8];
        // S^T tiles: sv[nt][r] = S^T[kk = nt*16+4g+r][q = i0+c] (pre-scaled, +bias)
        float sv[4][4];
#pragma unroll
        for (int nt = 0; nt < 4; ++nt) {
            fv4 z = {0.f, 0.f, 0.f, 0.f};
            fv4 s = __builtin_amdgcn_mfma_f32_16x16x32_bf16(kf[nt], qf[h], z, 0, 0, 0);
#pragma unroll
            for (int r = 0; r < 4; ++r)
                sv[nt][r] = s[r] * scale2 + brow[nt][r];
        }
        // softmax over kk for q=i0+c: in-lane 16 values + 2 shuffle rounds
        float m01 = fmaxf(fmaxf(sv[0][0], sv[0][1]), fmaxf(sv[0][2], sv[0][3]));
        float m11 = fmaxf(fmaxf(sv[1][0], sv[1][1]), fmaxf(sv[1][2], sv[1][3]));
        float m21 = fmaxf(fmaxf(sv[2][0], sv[2][1]), fmaxf(sv[2][2], sv[2][3]));
        float m31 = fmaxf(fmaxf(sv[3][0], sv[3][1]), fmaxf(sv[3][2], sv[3][3]));
        float mx = fmaxf(fmaxf(m01, m11), fmaxf(m21, m31));
        mx = fmaxf(mx, __shfl_xor(mx, 16, 64));
        mx = fmaxf(mx, __shfl_xor(mx, 32, 64));
        float sm = 0.f;
#pragma unroll
        for (int nt = 0; nt < 4; ++nt)
#pragma unroll
            for (int r = 0; r < 4; ++r) {
                float e = exp2f(sv[nt][r] - mx);
                sv[nt][r] = e;
                sm += e;
            }
        sm += __shfl_xor(sm, 16, 64);
        sm += __shfl_xor(sm, 32, 64);
        float inv = __builtin_amdgcn_rcpf(sm);

        // normalized P packed: pk[nt][b] = bf16x2 of (r=2b, r=2b+1)
        unsigned pk[4][2];
#pragma unroll
        for (int nt = 0; nt < 4; ++nt) {
            pk[nt][0] = pack2(sv[nt][0] * inv, sv[nt][1] * inv);
            pk[nt][1] = pack2(sv[nt][2] * inv, sv[nt][3] * inv);
        }
        // P fragment rebuild: pf[k2] word j2 holds P[q=i0+c][kk=32k2+8g+2j2, +1]
        // source lane: lsrc0 (j=0..3) / lsrc1 (j=4..7); nt' = 2k2 + (g>>1)
        bv8 pf[2];
#pragma unroll
        for (int k2 = 0; k2 < 2; ++k2) {
            unsigned w0 = (unsigned)__shfl((int)pk[2 * k2][0],     lsrc0, 64);
            unsigned w1 = (unsigned)__shfl((int)pk[2 * k2][1],     lsrc0, 64);
            unsigned w2 = (unsigned)__shfl((int)pk[2 * k2][0],     lsrc1, 64);
            unsigned w3 = (unsigned)__shfl((int)pk[2 * k2][1],     lsrc1, 64);
            unsigned v0 = (unsigned)__shfl((int)pk[2 * k2 + 1][0], lsrc0, 64);
            unsigned v1 = (unsigned)__shfl((int)pk[2 * k2 + 1][1], lsrc0, 64);
            unsigned v2 = (unsigned)__shfl((int)pk[2 * k2 + 1][0], lsrc1, 64);
            unsigned v3 = (unsigned)__shfl((int)pk[2 * k2 + 1][1], lsrc1, 64);
            unsigned u0 = selhi ? v0 : w0;   // j=0,1
            unsigned u1 = selhi ? v1 : w1;   // j=2,3
            unsigned u2 = selhi ? v2 : w2;   // j=4,5
            unsigned u3 = selhi ? v3 : w3;   // j=6,7
            bv8 p;
            p[0] = (short)(u0 & 0xffffu); p[1] = (short)(u0 >> 16);
            p[2] = (short)(u1 & 0xffffu); p[3] = (short)(u1 >> 16);
            p[4] = (short)(u2 & 0xffffu); p[5] = (short)(u2 >> 16);
            p[6] = (short)(u3 & 0xffffu); p[7] = (short)(u3 >> 16);
            pf[k2] = p;
        }
        // O strip = P @ V; D[q=4g+r][d=h*32+dt*16+c] -> auw overlay (own strip)
#pragma unroll
        for (int dt = 0; dt < 2; ++dt) {
            fv4 oacc = {0.f, 0.f, 0.f, 0.f};
#pragma unroll
            for (int k2 = 0; k2 < 2; ++k2) {
                bv8 vf = *(const bv8*)&vts[(h * 32 + dt * 16 + c) * 72 + k2 * 32 + g * 8];
                oacc = __builtin_amdgcn_mfma_f32_16x16x32_bf16(pf[k2], vf, oacc, 0, 0, 0);
            }
#pragma unroll
            for (int r = 0; r < 4; ++r)
                auw[(4 * g + r) * 104 + h * 32 + dt * 16 + c] = f2bf(oacc[r]);
        }
    }

    // ---- phase 4: out = A @ Wout + b on own strip (no barrier needed) ----
    bv8 afo[3];
#pragma unroll
    for (int k = 0; k < 3; ++k)
        afo[k] = *(const bv8*)&auw[c * 104 + k * 32 + g * 8];

    const unsigned short* osrc = woT + c * 96 + g * 8;
    bv8 ob0[3], obn[3];
#pragma unroll
    for (int k = 0; k < 3; ++k) ob0[k] = *(const bv8*)(osrc + k * 32);

#pragma unroll
    for (int nt = 0; nt < 6; ++nt) {
        if (nt < 5) {
#pragma unroll
            for (int k = 0; k < 3; ++k) obn[k] = *(const bv8*)(osrc + (nt + 1) * 1536 + k * 32);
        }
        fv4 acc = {0.f, 0.f, 0.f, 0.f};
#pragma unroll
        for (int k = 0; k < 3; ++k)
            acc = __builtin_amdgcn_mfma_f32_16x16x32_bf16(afo[k], ob0[k], acc, 0, 0, 0);
        int cc = nt * 16 + c;
        float bo = b_out[cc];
#pragma unroll
        for (int r = 0; r < 4; ++r) {
            int t = i0 + 4 * g + r;
            out[xbase + (t >> 4) * ST_H + ((t >> 2) & 3) * ST_W + (t & 3) * 96 + cc] = acc[r] + bo;
        }
#pragma unroll
        for (int k = 0; k < 3; ++k) ob0[k] = obn[k];
    }
}

extern "C" void kernel_launch(void* const* d_in, const int* in_sizes, int n_in,
                              void* d_out, int out_size, void* d_ws, size_t ws_size,
                              hipStream_t stream)
{
    const float* x    = (const float*)d_in[0];
    const float* wqkv = (const float*)d_in[1];
    const float* pos  = (const float*)d_in[2];
    const float* wout = (const float*)d_in[3];
    const float* bout = (const float*)d_in[4];
    float* out = (float*)d_out;

    float* biasT = (float*)d_ws;
    unsigned short* wqT = (unsigned short*)((char*)d_ws + 16384);
    unsigned short* woT = (unsigned short*)((char*)d_ws + 16384 + 55296);

    prep_kernel<<<160, 256, 0, stream>>>(wqkv, wout, pos, biasT, wqT, woT);
    winattn_kernel<<<dim3(4096, 2), 256, 0, stream>>>(x, bout, biasT, wqT, woT, out);
}